// Round 8
// baseline (225.167 us; speedup 1.0000x reference)
//
#include <hip/hip_runtime.h>
#include <math.h>

#define BB 16
#define MM 32
#define NN 8400
#define NCC 80
#define RMM 16
#define EPSF 1e-7f
#define NCHUNK 66            // ceil(8400/128): 128 rows per block, 2 threads/row
#define DGRID (2 * BB * NN * 16 / 256)   // 16800 blocks, one quarter per thread
#define DGRID_HALF (BB * NN * 16 / 256)  // 8400 blocks per branch
#define ROWP 81              // LDS row stride (floats): (17*rl+c)%32 covers all banks

typedef unsigned long long ull;

// ---------------------------------------------------------------------------
// ws layout (floats):
//   pdbox   : 2*BB*NN*4   ([rb*NN+n][4])
//   lse     : 2*BB*NN*4
//   topk1   : BB*MM*10 (int)
//   topk2   : BB*MM    (int)
//   partial : 2*BB*NCHUNK*8   (assign_loss per-block partials, q0..q5)
//     q: 0=sxt 1=box 2=dfl 3=nfg 4=mpos 5=softplus-sum
// ---------------------------------------------------------------------------

__device__ inline ull ullmax(ull a, ull b) { return a > b ? a : b; }
__device__ inline ull ullmin(ull a, ull b) { return a < b ? a : b; }

// Shared align-metric computation. __noinline__ => ONE codegen => bit-identical
// values in align_topk_kernel and assign_loss_kernel (assign's argmax must
// agree with topk's ordering on the same logical values).
__device__ __noinline__ float align_val(
    float px, float py, float pz, float pw,
    float g0, float g1, float g2, float g3, float x)
{
    float iw = fmaxf(fminf(pz, g2) - fmaxf(px, g0), 0.0f);
    float ih = fmaxf(fminf(pw, g3) - fmaxf(py, g1), 0.0f);
    float inter = iw * ih;
    float pa = (pz - px) * (pw - py);
    float ga = (g2 - g0) * (g3 - g1);
    float iou = inter / (pa + ga - inter + EPSF);
    float sig = __builtin_amdgcn_rcpf(1.0f + __expf(-x));
    float i2 = iou * iou;
    return sig * (i2 * i2 * i2);
}

__device__ inline float fast_softplus(float x) {
    float e = __expf(-fabsf(x));
    return fmaxf(x, 0.0f) + __logf(1.0f + e);
}

__device__ inline float sp4(float4 x) {
    return fast_softplus(x.x) + fast_softplus(x.y) +
           fast_softplus(x.z) + fast_softplus(x.w);
}

// ---- block reduce helper (result valid on thread 0) ------------------------
__device__ inline float blockReduceSum(float v, float* sh) {
    for (int o = 32; o > 0; o >>= 1) v += __shfl_down(v, o, 64);
    int lane = threadIdx.x & 63;
    int w = threadIdx.x >> 6;
    __syncthreads();
    if (lane == 0) sh[w] = v;
    __syncthreads();
    float r = 0.0f;
    if (threadIdx.x == 0) r = sh[0] + sh[1] + sh[2] + sh[3];
    return r;
}

// ---- kernel 1: decode only (quad-cooperative softmax), pure TLP ------------
// One round per thread, no loop, no LDS, minimal VGPR => max occupancy.
// All arithmetic / shuffle trees / lane mapping bit-identical to the
// previous passing version => pdbox/lse bitwise unchanged.
__global__ __launch_bounds__(256) void decode_kernel(
    const float* __restrict__ regs0, const float* __restrict__ regs1,
    const float* __restrict__ anchors, const float* __restrict__ strides,
    float* __restrict__ pdbox, float* __restrict__ lse)
{
    int tid = threadIdx.x;
    int l = tid & 63;
    int side = l & 3;
    int bg = (l >> 2) & 3;
    // permuted within-wave quarter offset: anchor-sub (l>>4)*16 + side*4 + bg
    int perm = (l & ~15) | (side << 2) | bg;

    const size_t QPB = (size_t)BB * NN * 16;        // quarters per branch
    int br = blockIdx.x >= DGRID_HALF;              // wave-uniform branch select
    size_t wbase = (size_t)blockIdx.x * 256 + (size_t)(tid & ~63);
    size_t Qp = wbase + (size_t)perm;               // global quarter index

    const float4* src = (const float4*)(br ? regs1 : regs0);
    float4 vv = src[Qp - (br ? QPB : (size_t)0)];   // fully coalesced (perm
                                                    // is a permutation of 64
                                                    // consecutive float4s)
    int A = (int)(Qp >> 4);                         // global anchor index
    int bn = A - br * (BB * NN);
    int n = bn % NN;
    float av  = anchors[2 * n + (side & 1)];
    float stv = strides[n];

    float mx = fmaxf(fmaxf(vv.x, vv.y), fmaxf(vv.z, vv.w));
    mx = fmaxf(mx, __shfl_xor(mx, 4));
    mx = fmaxf(mx, __shfl_xor(mx, 8));

    float w0 = (float)(bg * 4);
    float e0 = __expf(vv.x - mx), e1 = __expf(vv.y - mx);
    float e2 = __expf(vv.z - mx), e3 = __expf(vv.w - mx);
    float se = e0 + e1 + e2 + e3;
    float sd = e0 * w0 + e1 * (w0 + 1.0f) + e2 * (w0 + 2.0f) + e3 * (w0 + 3.0f);
    se += __shfl_xor(se, 4); se += __shfl_xor(se, 8);
    sd += __shfl_xor(sd, 4); sd += __shfl_xor(sd, 8);

    float d = sd * __builtin_amdgcn_rcpf(se);
    float lfin = mx + __logf(se);

    int idx4 = A * 4 + side;
    if (bg == 0) {
        float res = (side & 2) ? (av + d * stv) : (av - d * stv);
        pdbox[idx4] = res;
    } else if (bg == 1) {
        lse[idx4] = lfin;
    }
}

// ---- kernel 2: align + top-k via analytic in-box rectangle enumeration ----
// In-box anchors of gt [g0,g1,g2,g3] form a rectangle per anchor level
// (stride 8/16/32, grid 80/40/20). Enumerate rectangle candidates (widened
// +-1, re-tested with the EXACT reference float compares) plus candidates
// n=0..63 (reproduces lax.top_k zero-padding tie semantics; padding indices
// are provably within 0..63 since padding only occurs when <10 positives
// exist, leaving >=54 zero-align indices among 0..63). Rectangles skip n<64
// to avoid duplicates. key = (bits(al)<<32)|(NN-n): desc value, asc index.
__global__ __launch_bounds__(256) void align_topk_kernel(
    const float* __restrict__ cls0, const float* __restrict__ cls1,
    const int* __restrict__ gt_labels, const float* __restrict__ gt_bboxes,
    const float* __restrict__ pdbox,
    int* __restrict__ topk1, int* __restrict__ topk2)
{
    int r = blockIdx.x;                 // 0 .. 2*BB*MM-1
    int br = r / (BB * MM);
    int bm = r - br * (BB * MM);
    int b = bm / MM;
    int tid = threadIdx.x;

    const float* gt = gt_bboxes + (size_t)bm * 4;
    float g0 = gt[0], g1 = gt[1], g2 = gt[2], g3 = gt[3];
    int lab = gt_labels[bm];
    const float* clscol = (br == 0 ? cls0 : cls1) + (size_t)b * NN * NCC + lab;
    const float4* pb4 = (const float4*)pdbox + (size_t)(br * BB + b) * NN;

    const int lvl_s[3] = {8, 16, 32};
    const int lvl_g[3] = {80, 40, 20};
    const int lvl_b[3] = {0, 6400, 8000};

    // --- per-thread candidate scan -> sorted top-10 (branchless insert) ---
    ull loc[10];
#pragma unroll
    for (int j = 0; j < 10; ++j) loc[j] = 0ull;

    // fixed candidates n = 0..63 (level 0, gy=0, gx=n)
    if (tid < 64) {
        int n = tid;
        float ax = ((float)n + 0.5f) * 8.0f, ay = 4.0f;
        ull key = (ull)(unsigned)(NN - n);
        if (ax >= g0 && ax <= g2 && ay >= g1 && ay <= g3) {
            float4 pb = pb4[n];
            float x = clscol[(size_t)n * NCC];
            float al = align_val(pb.x, pb.y, pb.z, pb.w, g0, g1, g2, g3, x);
            key |= ((ull)__float_as_uint(al) << 32);
        }
#pragma unroll
        for (int j = 9; j >= 1; --j)
            loc[j] = ullmax(loc[j], ullmin(loc[j - 1], key));
        loc[0] = ullmax(loc[0], key);
    }

    // rectangle candidates per level
    for (int lvl = 0; lvl < 3; ++lvl) {
        int s = lvl_s[lvl], g = lvl_g[lvl], nb = lvl_b[lvl];
        float fs = (float)s;
        int x0 = (int)ceilf(g0 / fs - 0.5f) - 1; if (x0 < 0) x0 = 0;
        int x1 = (int)floorf(g2 / fs - 0.5f) + 1; if (x1 > g - 1) x1 = g - 1;
        int y0 = (int)ceilf(g1 / fs - 0.5f) - 1; if (y0 < 0) y0 = 0;
        int y1 = (int)floorf(g3 / fs - 0.5f) + 1; if (y1 > g - 1) y1 = g - 1;
        int rw = x1 - x0 + 1, rh = y1 - y0 + 1;
        if (rw <= 0 || rh <= 0) continue;
        int cnt = rw * rh;
        for (int c = tid; c < cnt; c += 256) {
            int gy = y0 + c / rw;
            int gx = x0 + c % rw;
            int n = nb + gy * g + gx;
            if (n < 64) continue;       // covered by fixed set
            float ax = ((float)gx + 0.5f) * fs;
            float ay = ((float)gy + 0.5f) * fs;
            if (!(ax >= g0 && ax <= g2 && ay >= g1 && ay <= g3)) continue;
            float4 pb = pb4[n];
            float x = clscol[(size_t)n * NCC];
            float al = align_val(pb.x, pb.y, pb.z, pb.w, g0, g1, g2, g3, x);
            ull key = ((ull)__float_as_uint(al) << 32) | (unsigned)(NN - n);
            if (key > loc[9]) {
#pragma unroll
                for (int j = 9; j >= 1; --j)
                    loc[j] = ullmax(loc[j], ullmin(loc[j - 1], key));
                loc[0] = ullmax(loc[0], key);
            }
        }
    }

    if (br == 1) {
        // k = 1: max-reduce of loc[0]
        ull best = loc[0];
        for (int o = 32; o > 0; o >>= 1) best = ullmax(best, __shfl_down(best, o, 64));
        __shared__ ull sm[4];
        int lane = tid & 63, w = tid >> 6;
        if (lane == 0) sm[w] = best;
        __syncthreads();
        if (tid == 0) {
            best = ullmax(ullmax(sm[0], sm[1]), ullmax(sm[2], sm[3]));
            topk2[bm] = NN - (int)(best & 0xffffffffull);
        }
        return;
    }

    // k = 10: LDS tree merge of sorted lists
    __shared__ ull ls[256 * 10];
#pragma unroll
    for (int j = 0; j < 10; ++j) ls[tid * 10 + j] = loc[j];
    __syncthreads();

    for (int s = 128; s > 0; s >>= 1) {
        if (tid < s) {
            ull* A = &ls[tid * 10];
            ull* B2 = &ls[(tid + s) * 10];
            ull o[10];
            int ia = 0, ib = 0;
#pragma unroll
            for (int j = 0; j < 10; ++j) {
                ull av = A[ia], bv = B2[ib];
                if (av >= bv) { o[j] = av; ++ia; }
                else          { o[j] = bv; ++ib; }
            }
#pragma unroll
            for (int j = 0; j < 10; ++j) A[j] = o[j];
        }
        __syncthreads();
    }
    if (tid < 10) topk1[bm * 10 + tid] = NN - (int)(ls[tid] & 0xffffffffull);
}

// ---- kernel 3: assignment + losses + LDS-staged cls (softplus fused) -------
// grid: (NCHUNK, 2*BB); 128 rows per block, TWO threads per row.
// partial[(rb*NCHUNK+cx)*8+q], q: 0=sxt 1=box 2=dfl 3=nfg 4=mpos 5=softplus
// Round-7 lesson: the harness fill proves 6.5 TB/s is reachable; our read
// kernels sit at ~2.5 TB/s aggregate. The remaining proven lever is byte/
// pass elimination. This round: cls is read EXACTLY ONCE here — each block
// stages its 128 rows into LDS (row stride 81 floats => (17*rl+c)%32 covers
// all 32 banks; the 2 pair-lanes broadcast => conflict-free reads), computes
// the softplus sum during the coalesced staging, and the argmax/BCE gathers
// read LDS instead of L2/global. Kills the separate 86MB softplus pass and
// assign's ~34MB scattered cls gather traffic. LDS 43.5KB => 3 blocks/CU.
__global__ __launch_bounds__(256) void assign_loss_kernel(
    const int* __restrict__ topk1, const int* __restrict__ topk2,
    const float* __restrict__ mask_gt,
    const int* __restrict__ gt_labels, const float* __restrict__ gt_bboxes,
    const float* __restrict__ cls0, const float* __restrict__ cls1,
    const float* __restrict__ regs0, const float* __restrict__ regs1,
    const float* __restrict__ anchors, const float* __restrict__ strides,
    const float* __restrict__ pdbox, const float* __restrict__ lse,
    float* __restrict__ partial)
{
    int cx = blockIdx.x;                 // 0..NCHUNK-1, 128 rows each
    int rb = blockIdx.y;                 // branch*BB + b
    int br = rb / BB;
    int b = rb - br * BB;
    int tid = threadIdx.x;
    int rl = tid >> 1;                   // local row 0..127
    int half = tid & 1;                  // m-range half
    int n = cx * 128 + rl;

    __shared__ float clsrow[128 * ROWP]; // 41472 B, bank-conflict-free reads
    __shared__ float g[MM * 4];
    __shared__ int gl[MM];
    __shared__ float gm[MM];
    __shared__ int tk[MM * 10];
    __shared__ int tk2s[MM];
    if (tid < MM * 4) g[tid] = gt_bboxes[b * MM * 4 + tid];
    if (tid < MM) {
        gl[tid] = gt_labels[b * MM + tid];
        gm[tid] = mask_gt[b * MM + tid];
        tk2s[tid] = topk2[b * MM + tid];
    }
    for (int j = tid; j < MM * 10; j += 256) tk[j] = topk1[b * MM * 10 + j];

    const float* cls = (br == 0 ? cls0 : cls1);

    // ---- coalesced stage of this block's cls rows into LDS + softplus -----
    int rows = NN - cx * 128; if (rows > 128) rows = 128;
    const float4* chunk4 = (const float4*)(cls + ((size_t)b * NN + (size_t)cx * 128) * NCC);
    int nf4 = rows * (NCC / 4);          // 2560 (1600 for the tail chunk)
    float ssp = 0.0f;
    for (int k = tid; k < nf4; k += 256) {
        int r = k / 20;                  // 20 float4 per row
        int c4 = k - r * 20;
        float4 x4 = chunk4[k];
        ssp += sp4(x4);
        float* dst = &clsrow[r * ROWP + c4 * 4];
        dst[0] = x4.x; dst[1] = x4.y; dst[2] = x4.z; dst[3] = x4.w;
    }

    __syncthreads();                     // covers clsrow + g/gl/gm/tk staging

    float sxt = 0.0f, sbox = 0.0f, sdfl = 0.0f, sfg = 0.0f, smp = 0.0f;

    if (n < NN) {
        const float* myrow = &clsrow[rl * ROWP];
        float2 anc = ((const float2*)anchors)[n];
        size_t i = (size_t)rb * NN + n;
        float4 pb = ((const float4*)pdbox)[i];

        // half-range argmax over m (bit-identical align values; x from LDS)
        float best = 0.0f;
        int mi = 0;
        for (int m = half * 16; m < half * 16 + 16; ++m) {
            float g0 = g[4 * m], g1 = g[4 * m + 1], g2 = g[4 * m + 2], g3 = g[4 * m + 3];
            if (anc.x >= g0 && anc.x <= g2 && anc.y >= g1 && anc.y <= g3) {
                float x = myrow[gl[m]];
                float al = align_val(pb.x, pb.y, pb.z, pb.w, g0, g1, g2, g3, x);
                if (al > best) { best = al; mi = m; }
            }
        }
        // pair-combine (lanes 2i <-> 2i+1, same wave, both active since n
        // is uniform within the pair)
        float bo = __shfl_xor(best, 1);
        int mio = __shfl_xor(mi, 1);

        if (half == 0) {
            if (bo > best) { best = bo; mi = mio; }   // odd half wins only strictly

            int ind = 0;
            if (br == 0) {
                const int* tkp = &tk[mi * 10];
#pragma unroll
                for (int j = 0; j < 10; ++j)
                    if (tkp[j] == n) ind = 1;
            } else {
                if (tk2s[mi] == n) ind = 1;
            }
            float mp = ind ? gm[mi] : 0.0f;
            smp = mp;
            if (mp > 0.0f) {
                sfg = 1.0f;
                float t0 = g[4 * mi] * mp, t1 = g[4 * mi + 1] * mp;
                float t2 = g[4 * mi + 2] * mp, t3 = g[4 * mi + 3] * mp;

                // plain IoU (for tscores)
                float iw = fmaxf(fminf(pb.z, t2) - fmaxf(pb.x, t0), 0.0f);
                float ih = fmaxf(fminf(pb.w, t3) - fmaxf(pb.y, t1), 0.0f);
                float inter = iw * ih;
                float w1 = pb.z - pb.x, h1 = pb.w - pb.y;
                float w2 = t2 - t0, h2 = t3 - t1;
                float uni = w1 * h1 + w2 * h2 - inter + EPSF;
                float iou = inter / uni;

                // -x*t term of BCE (x from LDS, bit-identical value)
                float x = myrow[gl[mi]];
                sxt = x * iou;

                // CIoU (replicating reference's ch bug: ch = max(y2) - b1y1)
                float cw = fmaxf(pb.z, t2) - fminf(pb.x, t0);
                float ch = fmaxf(pb.w, t3) - pb.y;     // BUG in reference, replicated
                float c2 = cw * cw + ch * ch + EPSF;
                float dx = pb.x + pb.z - t0 - t2;
                float dy = pb.y + pb.w - t1 - t3;
                float rho2 = (dx * dx + dy * dy) * 0.25f;
                float dat = atanf(w2 / (h2 + EPSF)) - atanf(w1 / (h1 + EPSF));
                float v = 0.40528473f * dat * dat;     // 4/pi^2
                float alpha_ = v / (v - iou + 1.0000001f);
                float ciou = iou - (rho2 / c2 + v * alpha_);
                sbox = 1.0f - ciou;

                // DFL
                float st = strides[n];
                float tb[4] = {(anc.x - t0) / st, (anc.y - t1) / st,
                               (t2 - anc.x) / st, (t3 - anc.y) / st};
                float4 l4 = ((const float4*)lse)[i];
                float lv[4] = {l4.x, l4.y, l4.z, l4.w};
                const float* regs = (br == 0 ? regs0 : regs1) + ((size_t)b * NN + n) * 64;
                float dsum = 0.0f;
#pragma unroll
                for (int s2 = 0; s2 < 4; ++s2) {
                    float t = fminf(fmaxf(tb[s2], 0.0f), (float)RMM - 1.01f);
                    int tl = (int)t;
                    float wl = (float)(tl + 1) - t;
                    float wr = 1.0f - wl;
                    float lp_l = regs[s2 * 16 + tl] - lv[s2];
                    float lp_r = regs[s2 * 16 + tl + 1] - lv[s2];
                    dsum += -(lp_l * wl + lp_r * wr);
                }
                sdfl = dsum;
            }
        }
    }

    __shared__ float sh[4];
    float vals[6] = {sxt, sbox, sdfl, sfg, smp, ssp};
    float* outp = partial + ((size_t)rb * NCHUNK + cx) * 8;
#pragma unroll
    for (int q = 0; q < 6; ++q) {
        float r = blockReduceSum(vals[q], sh);
        if (tid == 0) outp[q] = r;
        __syncthreads();
    }
}

// ---- kernel 4: finalize (reduce all partials, emit 6 outputs) --------------
__global__ __launch_bounds__(256) void finalize_kernel(
    const float* __restrict__ partial,
    float* __restrict__ out)
{
    int tid = threadIdx.x;
    float s[12];
#pragma unroll
    for (int j = 0; j < 12; ++j) s[j] = 0.0f;
    const int nblk = 2 * BB * NCHUNK;
    for (int blk = tid; blk < nblk; blk += 256) {
        int br = blk / (BB * NCHUNK);
#pragma unroll
        for (int q = 0; q < 6; ++q) s[br * 6 + q] += partial[(size_t)blk * 8 + q];
    }

    __shared__ float sh[4];
    __shared__ float res[12];
#pragma unroll
    for (int j = 0; j < 12; ++j) {
        float r = blockReduceSum(s[j], sh);
        if (tid == 0) res[j] = r;
        __syncthreads();
    }

    if (tid == 0) {
        float t[2], c[2], bx[2], df[2];
        for (int br = 0; br < 2; ++br) {
            float a0 = res[br * 6 + 0], a1 = res[br * 6 + 1], a2 = res[br * 6 + 2];
            float a3 = res[br * 6 + 3], a4 = res[br * 6 + 4];
            float sp = res[br * 6 + 5];
            float nfg = fmaxf(a3, 1.0f);
            float lcls = (sp - a0) / fmaxf(a4, 1.0f);
            float lbox = a1 / nfg;
            float ldfl = a2 / (nfg * 4.0f);
            t[br] = lcls * 1.0f + lbox * 7.5f + ldfl * 1.5f;
            c[br] = lcls;
            bx[br] = lbox;
            df[br] = ldfl;
        }
        out[0] = t[0] + t[1];
        out[1] = c[0] + c[1];
        out[2] = bx[0] + bx[1];
        out[3] = df[0] + df[1];
        out[4] = t[0];
        out[5] = t[1];
    }
}

// ---------------------------------------------------------------------------
extern "C" void kernel_launch(void* const* d_in, const int* in_sizes, int n_in,
                              void* d_out, int out_size, void* d_ws, size_t ws_size,
                              hipStream_t stream) {
    const float* cls0    = (const float*)d_in[0];  // cls_scores
    const float* regs0   = (const float*)d_in[1];  // box_regs
    const float* cls1    = (const float*)d_in[2];  // one2one_cls
    const float* regs1   = (const float*)d_in[3];  // one2one_reg
    const float* anchors = (const float*)d_in[4];
    const float* strides = (const float*)d_in[5];
    const int*   gt_labels = (const int*)d_in[6];
    const float* gt_bboxes = (const float*)d_in[7];
    const float* mask_gt   = (const float*)d_in[8];
    float* out = (float*)d_out;

    float* pdbox   = (float*)d_ws;                       // 2*BB*NN*4
    float* lse     = pdbox + (size_t)2 * BB * NN * 4;    // 2*BB*NN*4
    int*   topk1   = (int*)(lse + (size_t)2 * BB * NN * 4);  // BB*MM*10
    int*   topk2   = topk1 + BB * MM * 10;               // BB*MM
    float* partial = (float*)(topk2 + BB * MM);          // 2*BB*NCHUNK*8

    decode_kernel<<<DGRID, 256, 0, stream>>>(
        regs0, regs1, anchors, strides, pdbox, lse);

    align_topk_kernel<<<2 * BB * MM, 256, 0, stream>>>(
        cls0, cls1, gt_labels, gt_bboxes, pdbox, topk1, topk2);

    dim3 agrid(NCHUNK, 2 * BB);
    assign_loss_kernel<<<agrid, 256, 0, stream>>>(
        topk1, topk2, mask_gt, gt_labels, gt_bboxes,
        cls0, cls1, regs0, regs1, anchors, strides, pdbox, lse, partial);

    finalize_kernel<<<1, 256, 0, stream>>>(partial, out);
}

// Round 9
// 209.778 us; speedup vs baseline: 1.0734x; 1.0734x over previous
//
#include <hip/hip_runtime.h>
#include <math.h>

#define BB 16
#define MM 32
#define NN 8400
#define NCC 80
#define RMM 16
#define EPSF 1e-7f
#define NCHUNK 66            // ceil(8400/128): 128 rows per block, 2 threads/row
#define DGRID (2 * BB * NN * 16 / 256)   // 16800 blocks, one quarter per thread
#define DGRID_HALF (BB * NN * 16 / 256)  // 8400 blocks per branch
#define ABLOCKS (2 * BB * MM)            // 1024 align blocks
#define ASTR ((size_t)ABLOCKS * 256)     // softplus grid stride = 262144

typedef unsigned long long ull;

// ---------------------------------------------------------------------------
// ws layout (floats):
//   pdbox   : 2*BB*NN*4   ([rb*NN+n][4])
//   lse     : 2*BB*NN*4
//   topk1   : BB*MM*10 (int)
//   topk2   : BB*MM    (int)
//   partial : 2*BB*NCHUNK*8   (assign_loss per-block partials, q0..q4)
//   psp     : ABLOCKS*2       (softplus partials, written by align_topk)
// ---------------------------------------------------------------------------

__device__ inline ull ullmax(ull a, ull b) { return a > b ? a : b; }
__device__ inline ull ullmin(ull a, ull b) { return a < b ? a : b; }

// Shared align-metric computation. __noinline__ => ONE codegen => bit-identical
// values in align_topk_kernel and assign_loss_kernel (assign's argmax must
// agree with topk's ordering on the same logical values).
__device__ __noinline__ float align_val(
    float px, float py, float pz, float pw,
    float g0, float g1, float g2, float g3, float x)
{
    float iw = fmaxf(fminf(pz, g2) - fmaxf(px, g0), 0.0f);
    float ih = fmaxf(fminf(pw, g3) - fmaxf(py, g1), 0.0f);
    float inter = iw * ih;
    float pa = (pz - px) * (pw - py);
    float ga = (g2 - g0) * (g3 - g1);
    float iou = inter / (pa + ga - inter + EPSF);
    float sig = __builtin_amdgcn_rcpf(1.0f + __expf(-x));
    float i2 = iou * iou;
    return sig * (i2 * i2 * i2);
}

__device__ inline float fast_softplus(float x) {
    float e = __expf(-fabsf(x));
    return fmaxf(x, 0.0f) + __logf(1.0f + e);
}

__device__ inline float sp4(float4 x) {
    return fast_softplus(x.x) + fast_softplus(x.y) +
           fast_softplus(x.z) + fast_softplus(x.w);
}

// ---- block reduce helper (result valid on thread 0) ------------------------
__device__ inline float blockReduceSum(float v, float* sh) {
    for (int o = 32; o > 0; o >>= 1) v += __shfl_down(v, o, 64);
    int lane = threadIdx.x & 63;
    int w = threadIdx.x >> 6;
    __syncthreads();
    if (lane == 0) sh[w] = v;
    __syncthreads();
    float r = 0.0f;
    if (threadIdx.x == 0) r = sh[0] + sh[1] + sh[2] + sh[3];
    return r;
}

// ---- kernel 1: decode only (quad-cooperative softmax), pure TLP ------------
// One round per thread, no loop, no LDS, minimal VGPR => max occupancy.
// All arithmetic / shuffle trees / lane mapping bit-identical to the
// previous passing version => pdbox/lse bitwise unchanged.
__global__ __launch_bounds__(256) void decode_kernel(
    const float* __restrict__ regs0, const float* __restrict__ regs1,
    const float* __restrict__ anchors, const float* __restrict__ strides,
    float* __restrict__ pdbox, float* __restrict__ lse)
{
    int tid = threadIdx.x;
    int l = tid & 63;
    int side = l & 3;
    int bg = (l >> 2) & 3;
    // permuted within-wave quarter offset: anchor-sub (l>>4)*16 + side*4 + bg
    int perm = (l & ~15) | (side << 2) | bg;

    const size_t QPB = (size_t)BB * NN * 16;        // quarters per branch
    int br = blockIdx.x >= DGRID_HALF;              // wave-uniform branch select
    size_t wbase = (size_t)blockIdx.x * 256 + (size_t)(tid & ~63);
    size_t Qp = wbase + (size_t)perm;               // global quarter index

    const float4* src = (const float4*)(br ? regs1 : regs0);
    float4 vv = src[Qp - (br ? QPB : (size_t)0)];   // fully coalesced (perm
                                                    // is a permutation of 64
                                                    // consecutive float4s)
    int A = (int)(Qp >> 4);                         // global anchor index
    int bn = A - br * (BB * NN);
    int n = bn % NN;
    float av  = anchors[2 * n + (side & 1)];
    float stv = strides[n];

    float mx = fmaxf(fmaxf(vv.x, vv.y), fmaxf(vv.z, vv.w));
    mx = fmaxf(mx, __shfl_xor(mx, 4));
    mx = fmaxf(mx, __shfl_xor(mx, 8));

    float w0 = (float)(bg * 4);
    float e0 = __expf(vv.x - mx), e1 = __expf(vv.y - mx);
    float e2 = __expf(vv.z - mx), e3 = __expf(vv.w - mx);
    float se = e0 + e1 + e2 + e3;
    float sd = e0 * w0 + e1 * (w0 + 1.0f) + e2 * (w0 + 2.0f) + e3 * (w0 + 3.0f);
    se += __shfl_xor(se, 4); se += __shfl_xor(se, 8);
    sd += __shfl_xor(sd, 4); sd += __shfl_xor(sd, 8);

    float d = sd * __builtin_amdgcn_rcpf(se);
    float lfin = mx + __logf(se);

    int idx4 = A * 4 + side;
    if (bg == 0) {
        float res = (side & 2) ? (av + d * stv) : (av - d * stv);
        pdbox[idx4] = res;
    } else if (bg == 1) {
        lse[idx4] = lfin;
    }
}

// ---- kernel 2: align + top-k + FUSED softplus stream -----------------------
// Round-8 lesson: LDS-staging L2-resident cls regressed (bank conflicts
// 1.75M, occupancy 27%); reverted. This round consolidates: the standalone
// softplus kernel is folded here as a grid-stride phase — this kernel's
// 262,144 threads are mostly idle after the candidate scan (~2 candidates
// per thread), and it already touches cls. Kills one dispatch (~10us fixed)
// and fills idle capacity. Softplus partition change is output-invariant
// (established r2->r3->r7).
// Top-k logic unchanged: analytic in-box rectangle enumeration + fixed
// n=0..63 (lax.top_k zero-padding tie semantics), key=(bits(al)<<32)|(NN-n).
__global__ __launch_bounds__(256) void align_topk_kernel(
    const float* __restrict__ cls0, const float* __restrict__ cls1,
    const int* __restrict__ gt_labels, const float* __restrict__ gt_bboxes,
    const float* __restrict__ pdbox,
    int* __restrict__ topk1, int* __restrict__ topk2,
    float* __restrict__ psp)
{
    int r = blockIdx.x;                 // 0 .. 2*BB*MM-1
    int br = r / (BB * MM);
    int bm = r - br * (BB * MM);
    int b = bm / MM;
    int tid = threadIdx.x;

    // ---- fused softplus stream over both cls tensors (grid-stride) --------
    {
        const size_t half4 = (size_t)BB * NN * NCC / 4;   // 2,688,000
        const float4* c0 = (const float4*)cls0;
        const float4* c1 = (const float4*)cls1;
        float s0 = 0.0f, s1 = 0.0f;
        for (size_t idx = (size_t)r * 256 + (size_t)tid; idx < 2 * half4; idx += ASTR) {
            int b2 = idx >= half4;
            float4 v = b2 ? c1[idx - half4] : c0[idx];
            float s = sp4(v);
            if (b2) s1 += s; else s0 += s;
        }
        __shared__ float shs[4];
        float r0 = blockReduceSum(s0, shs);
        __syncthreads();
        float r1 = blockReduceSum(s1, shs);
        if (tid == 0) {
            psp[r * 2 + 0] = r0;
            psp[r * 2 + 1] = r1;
        }
        __syncthreads();
    }

    const float* gt = gt_bboxes + (size_t)bm * 4;
    float g0 = gt[0], g1 = gt[1], g2 = gt[2], g3 = gt[3];
    int lab = gt_labels[bm];
    const float* clscol = (br == 0 ? cls0 : cls1) + (size_t)b * NN * NCC + lab;
    const float4* pb4 = (const float4*)pdbox + (size_t)(br * BB + b) * NN;

    const int lvl_s[3] = {8, 16, 32};
    const int lvl_g[3] = {80, 40, 20};
    const int lvl_b[3] = {0, 6400, 8000};

    // --- per-thread candidate scan -> sorted top-10 (branchless insert) ---
    ull loc[10];
#pragma unroll
    for (int j = 0; j < 10; ++j) loc[j] = 0ull;

    // fixed candidates n = 0..63 (level 0, gy=0, gx=n)
    if (tid < 64) {
        int n = tid;
        float ax = ((float)n + 0.5f) * 8.0f, ay = 4.0f;
        ull key = (ull)(unsigned)(NN - n);
        if (ax >= g0 && ax <= g2 && ay >= g1 && ay <= g3) {
            float4 pb = pb4[n];
            float x = clscol[(size_t)n * NCC];
            float al = align_val(pb.x, pb.y, pb.z, pb.w, g0, g1, g2, g3, x);
            key |= ((ull)__float_as_uint(al) << 32);
        }
#pragma unroll
        for (int j = 9; j >= 1; --j)
            loc[j] = ullmax(loc[j], ullmin(loc[j - 1], key));
        loc[0] = ullmax(loc[0], key);
    }

    // rectangle candidates per level
    for (int lvl = 0; lvl < 3; ++lvl) {
        int s = lvl_s[lvl], g = lvl_g[lvl], nb = lvl_b[lvl];
        float fs = (float)s;
        int x0 = (int)ceilf(g0 / fs - 0.5f) - 1; if (x0 < 0) x0 = 0;
        int x1 = (int)floorf(g2 / fs - 0.5f) + 1; if (x1 > g - 1) x1 = g - 1;
        int y0 = (int)ceilf(g1 / fs - 0.5f) - 1; if (y0 < 0) y0 = 0;
        int y1 = (int)floorf(g3 / fs - 0.5f) + 1; if (y1 > g - 1) y1 = g - 1;
        int rw = x1 - x0 + 1, rh = y1 - y0 + 1;
        if (rw <= 0 || rh <= 0) continue;
        int cnt = rw * rh;
        for (int c = tid; c < cnt; c += 256) {
            int gy = y0 + c / rw;
            int gx = x0 + c % rw;
            int n = nb + gy * g + gx;
            if (n < 64) continue;       // covered by fixed set
            float ax = ((float)gx + 0.5f) * fs;
            float ay = ((float)gy + 0.5f) * fs;
            if (!(ax >= g0 && ax <= g2 && ay >= g1 && ay <= g3)) continue;
            float4 pb = pb4[n];
            float x = clscol[(size_t)n * NCC];
            float al = align_val(pb.x, pb.y, pb.z, pb.w, g0, g1, g2, g3, x);
            ull key = ((ull)__float_as_uint(al) << 32) | (unsigned)(NN - n);
            if (key > loc[9]) {
#pragma unroll
                for (int j = 9; j >= 1; --j)
                    loc[j] = ullmax(loc[j], ullmin(loc[j - 1], key));
                loc[0] = ullmax(loc[0], key);
            }
        }
    }

    if (br == 1) {
        // k = 1: max-reduce of loc[0]
        ull best = loc[0];
        for (int o = 32; o > 0; o >>= 1) best = ullmax(best, __shfl_down(best, o, 64));
        __shared__ ull sm[4];
        int lane = tid & 63, w = tid >> 6;
        if (lane == 0) sm[w] = best;
        __syncthreads();
        if (tid == 0) {
            best = ullmax(ullmax(sm[0], sm[1]), ullmax(sm[2], sm[3]));
            topk2[bm] = NN - (int)(best & 0xffffffffull);
        }
        return;
    }

    // k = 10: LDS tree merge of sorted lists
    __shared__ ull ls[256 * 10];
#pragma unroll
    for (int j = 0; j < 10; ++j) ls[tid * 10 + j] = loc[j];
    __syncthreads();

    for (int s = 128; s > 0; s >>= 1) {
        if (tid < s) {
            ull* A = &ls[tid * 10];
            ull* B2 = &ls[(tid + s) * 10];
            ull o[10];
            int ia = 0, ib = 0;
#pragma unroll
            for (int j = 0; j < 10; ++j) {
                ull av = A[ia], bv = B2[ib];
                if (av >= bv) { o[j] = av; ++ia; }
                else          { o[j] = bv; ++ib; }
            }
#pragma unroll
            for (int j = 0; j < 10; ++j) A[j] = o[j];
        }
        __syncthreads();
    }
    if (tid < 10) topk1[bm * 10 + tid] = NN - (int)(ls[tid] & 0xffffffffull);
}

// ---- kernel 3: assignment + fg-only losses (round-7 form, reverted) --------
// grid: (NCHUNK, 2*BB); 128 rows per block, TWO threads per row.
// partial[(rb*NCHUNK+cx)*8+q], q: 0=sxt 1=box 2=dfl 3=nfg 4=mpos
__global__ __launch_bounds__(256) void assign_loss_kernel(
    const int* __restrict__ topk1, const int* __restrict__ topk2,
    const float* __restrict__ mask_gt,
    const int* __restrict__ gt_labels, const float* __restrict__ gt_bboxes,
    const float* __restrict__ cls0, const float* __restrict__ cls1,
    const float* __restrict__ regs0, const float* __restrict__ regs1,
    const float* __restrict__ anchors, const float* __restrict__ strides,
    const float* __restrict__ pdbox, const float* __restrict__ lse,
    float* __restrict__ partial)
{
    int cx = blockIdx.x;                 // 0..NCHUNK-1, 128 rows each
    int rb = blockIdx.y;                 // branch*BB + b
    int br = rb / BB;
    int b = rb - br * BB;
    int tid = threadIdx.x;
    int rl = tid >> 1;                   // local row 0..127
    int half = tid & 1;                  // m-range half
    int n = cx * 128 + rl;

    __shared__ float g[MM * 4];
    __shared__ int gl[MM];
    __shared__ float gm[MM];
    __shared__ int tk[MM * 10];
    __shared__ int tk2s[MM];
    if (tid < MM * 4) g[tid] = gt_bboxes[b * MM * 4 + tid];
    if (tid < MM) {
        gl[tid] = gt_labels[b * MM + tid];
        gm[tid] = mask_gt[b * MM + tid];
        tk2s[tid] = topk2[b * MM + tid];
    }
    for (int j = tid; j < MM * 10; j += 256) tk[j] = topk1[b * MM * 10 + j];
    __syncthreads();

    const float* cls = (br == 0 ? cls0 : cls1);
    float sxt = 0.0f, sbox = 0.0f, sdfl = 0.0f, sfg = 0.0f, smp = 0.0f;

    if (n < NN) {
        const float* cp = cls + ((size_t)b * NN + n) * NCC;
        float2 anc = ((const float2*)anchors)[n];
        size_t i = (size_t)rb * NN + n;
        float4 pb = ((const float4*)pdbox)[i];

        // half-range argmax over m (bit-identical align values)
        float best = 0.0f;
        int mi = 0;
        for (int m = half * 16; m < half * 16 + 16; ++m) {
            float g0 = g[4 * m], g1 = g[4 * m + 1], g2 = g[4 * m + 2], g3 = g[4 * m + 3];
            if (anc.x >= g0 && anc.x <= g2 && anc.y >= g1 && anc.y <= g3) {
                float x = cp[gl[m]];
                float al = align_val(pb.x, pb.y, pb.z, pb.w, g0, g1, g2, g3, x);
                if (al > best) { best = al; mi = m; }
            }
        }
        // pair-combine (lanes 2i <-> 2i+1, same wave, both active since n
        // is uniform within the pair)
        float bo = __shfl_xor(best, 1);
        int mio = __shfl_xor(mi, 1);

        if (half == 0) {
            if (bo > best) { best = bo; mi = mio; }   // odd half wins only strictly

            int ind = 0;
            if (br == 0) {
                const int* tkp = &tk[mi * 10];
#pragma unroll
                for (int j = 0; j < 10; ++j)
                    if (tkp[j] == n) ind = 1;
            } else {
                if (tk2s[mi] == n) ind = 1;
            }
            float mp = ind ? gm[mi] : 0.0f;
            smp = mp;
            if (mp > 0.0f) {
                sfg = 1.0f;
                float t0 = g[4 * mi] * mp, t1 = g[4 * mi + 1] * mp;
                float t2 = g[4 * mi + 2] * mp, t3 = g[4 * mi + 3] * mp;

                // plain IoU (for tscores)
                float iw = fmaxf(fminf(pb.z, t2) - fmaxf(pb.x, t0), 0.0f);
                float ih = fmaxf(fminf(pb.w, t3) - fmaxf(pb.y, t1), 0.0f);
                float inter = iw * ih;
                float w1 = pb.z - pb.x, h1 = pb.w - pb.y;
                float w2 = t2 - t0, h2 = t3 - t1;
                float uni = w1 * h1 + w2 * h2 - inter + EPSF;
                float iou = inter / uni;

                // -x*t term of BCE
                float x = cp[gl[mi]];
                sxt = x * iou;

                // CIoU (replicating reference's ch bug: ch = max(y2) - b1y1)
                float cw = fmaxf(pb.z, t2) - fminf(pb.x, t0);
                float ch = fmaxf(pb.w, t3) - pb.y;     // BUG in reference, replicated
                float c2 = cw * cw + ch * ch + EPSF;
                float dx = pb.x + pb.z - t0 - t2;
                float dy = pb.y + pb.w - t1 - t3;
                float rho2 = (dx * dx + dy * dy) * 0.25f;
                float dat = atanf(w2 / (h2 + EPSF)) - atanf(w1 / (h1 + EPSF));
                float v = 0.40528473f * dat * dat;     // 4/pi^2
                float alpha_ = v / (v - iou + 1.0000001f);
                float ciou = iou - (rho2 / c2 + v * alpha_);
                sbox = 1.0f - ciou;

                // DFL
                float st = strides[n];
                float tb[4] = {(anc.x - t0) / st, (anc.y - t1) / st,
                               (t2 - anc.x) / st, (t3 - anc.y) / st};
                float4 l4 = ((const float4*)lse)[i];
                float lv[4] = {l4.x, l4.y, l4.z, l4.w};
                const float* regs = (br == 0 ? regs0 : regs1) + ((size_t)b * NN + n) * 64;
                float dsum = 0.0f;
#pragma unroll
                for (int s2 = 0; s2 < 4; ++s2) {
                    float t = fminf(fmaxf(tb[s2], 0.0f), (float)RMM - 1.01f);
                    int tl = (int)t;
                    float wl = (float)(tl + 1) - t;
                    float wr = 1.0f - wl;
                    float lp_l = regs[s2 * 16 + tl] - lv[s2];
                    float lp_r = regs[s2 * 16 + tl + 1] - lv[s2];
                    dsum += -(lp_l * wl + lp_r * wr);
                }
                sdfl = dsum;
            }
        }
    }

    __shared__ float sh[4];
    float vals[5] = {sxt, sbox, sdfl, sfg, smp};
    float* outp = partial + ((size_t)rb * NCHUNK + cx) * 8;
#pragma unroll
    for (int q = 0; q < 5; ++q) {
        float r = blockReduceSum(vals[q], sh);
        if (tid == 0) outp[q] = r;
        __syncthreads();
    }
}

// ---- kernel 4: finalize (reduce all partials, emit 6 outputs) --------------
__global__ __launch_bounds__(256) void finalize_kernel(
    const float* __restrict__ partial, const float* __restrict__ psp,
    float* __restrict__ out)
{
    int tid = threadIdx.x;
    float s[10];
#pragma unroll
    for (int j = 0; j < 10; ++j) s[j] = 0.0f;
    const int nblk = 2 * BB * NCHUNK;
    for (int blk = tid; blk < nblk; blk += 256) {
        int br = blk / (BB * NCHUNK);
#pragma unroll
        for (int q = 0; q < 5; ++q) s[br * 5 + q] += partial[(size_t)blk * 8 + q];
    }
    float sp0 = 0.0f, sp1 = 0.0f;
    for (int i = tid; i < ABLOCKS; i += 256) {
        sp0 += psp[2 * i];
        sp1 += psp[2 * i + 1];
    }

    __shared__ float sh[4];
    __shared__ float res[12];
#pragma unroll
    for (int j = 0; j < 10; ++j) {
        float r = blockReduceSum(s[j], sh);
        if (tid == 0) res[j] = r;
        __syncthreads();
    }
    {
        float r = blockReduceSum(sp0, sh);
        if (tid == 0) res[10] = r;
        __syncthreads();
        r = blockReduceSum(sp1, sh);
        if (tid == 0) res[11] = r;
        __syncthreads();
    }

    if (tid == 0) {
        float t[2], c[2], bx[2], df[2];
        for (int br = 0; br < 2; ++br) {
            float a0 = res[br * 5 + 0], a1 = res[br * 5 + 1], a2 = res[br * 5 + 2];
            float a3 = res[br * 5 + 3], a4 = res[br * 5 + 4];
            float sp = res[10 + br];
            float nfg = fmaxf(a3, 1.0f);
            float lcls = (sp - a0) / fmaxf(a4, 1.0f);
            float lbox = a1 / nfg;
            float ldfl = a2 / (nfg * 4.0f);
            t[br] = lcls * 1.0f + lbox * 7.5f + ldfl * 1.5f;
            c[br] = lcls;
            bx[br] = lbox;
            df[br] = ldfl;
        }
        out[0] = t[0] + t[1];
        out[1] = c[0] + c[1];
        out[2] = bx[0] + bx[1];
        out[3] = df[0] + df[1];
        out[4] = t[0];
        out[5] = t[1];
    }
}

// ---------------------------------------------------------------------------
extern "C" void kernel_launch(void* const* d_in, const int* in_sizes, int n_in,
                              void* d_out, int out_size, void* d_ws, size_t ws_size,
                              hipStream_t stream) {
    const float* cls0    = (const float*)d_in[0];  // cls_scores
    const float* regs0   = (const float*)d_in[1];  // box_regs
    const float* cls1    = (const float*)d_in[2];  // one2one_cls
    const float* regs1   = (const float*)d_in[3];  // one2one_reg
    const float* anchors = (const float*)d_in[4];
    const float* strides = (const float*)d_in[5];
    const int*   gt_labels = (const int*)d_in[6];
    const float* gt_bboxes = (const float*)d_in[7];
    const float* mask_gt   = (const float*)d_in[8];
    float* out = (float*)d_out;

    float* pdbox   = (float*)d_ws;                       // 2*BB*NN*4
    float* lse     = pdbox + (size_t)2 * BB * NN * 4;    // 2*BB*NN*4
    int*   topk1   = (int*)(lse + (size_t)2 * BB * NN * 4);  // BB*MM*10
    int*   topk2   = topk1 + BB * MM * 10;               // BB*MM
    float* partial = (float*)(topk2 + BB * MM);          // 2*BB*NCHUNK*8
    float* psp     = partial + (size_t)2 * BB * NCHUNK * 8;  // ABLOCKS*2

    decode_kernel<<<DGRID, 256, 0, stream>>>(
        regs0, regs1, anchors, strides, pdbox, lse);

    align_topk_kernel<<<ABLOCKS, 256, 0, stream>>>(
        cls0, cls1, gt_labels, gt_bboxes, pdbox, topk1, topk2, psp);

    dim3 agrid(NCHUNK, 2 * BB);
    assign_loss_kernel<<<agrid, 256, 0, stream>>>(
        topk1, topk2, mask_gt, gt_labels, gt_bboxes,
        cls0, cls1, regs0, regs1, anchors, strides, pdbox, lse, partial);

    finalize_kernel<<<1, 256, 0, stream>>>(partial, psp, out);
}